// Round 8
// baseline (107.111 us; speedup 1.0000x reference)
//
#include <hip/hip_runtime.h>
#include <hip/hip_bf16.h>
#include <math.h>

// Problem constants: B=2, C=256, H=W=64 -> HW=4096
#define BB 2
#define CC 256
#define HWN 4096
#define PPB 8              // pixels per prep block (small blocks -> 4/CU overlap)
#define CCP 260            // LDS row stride in shorts: 520B, 8B-aligned, stores 2-way

// Fragment-blocked fp8 layout (per batch): for row r (pixel), k-byte kb:
//   addr = (r>>4)*4096 + (kb>>5)*512 + (r&15)*32 + (kb&31)
// => an MFMA fragment load (16 rows x 32 k-bytes, lane L: row L&15,
//    kb (L>>4)*32) is ONE contiguous 2KB wave transaction. No LDS needed.

typedef __attribute__((ext_vector_type(4))) int   intx4;
typedef __attribute__((ext_vector_type(8))) int   intx8;
typedef __attribute__((ext_vector_type(4))) float floatx4;

__device__ __forceinline__ unsigned short f2bf(float f) {
    union { float f; unsigned u; } v; v.f = f;
    unsigned r = v.u + 0x7FFF + ((v.u >> 16) & 1);   // RNE
    return (unsigned short)(r >> 16);
}

__device__ __forceinline__ float bf2f(unsigned short h) {
    union { unsigned u; float f; } v; v.u = ((unsigned)h) << 16;
    return v.f;
}

// Fused prep: one block per (batch, 8-pixel chunk), 256 threads, 12.7 KB LDS
// -> grid 1024 = 4 blocks/CU so the serial phase chain pipelines across
// blocks (R4 lesson: 1 block/CU left CUs idle at every phase transition).
// Reads dv/di/df once (coalesced float4), norms via shuffle+LDS, transposes
// through LDS, packs fp8 into the fragment-blocked layout.
__global__ __launch_bounds__(256) void prep_kernel(
    const float* __restrict__ sv, const float* __restrict__ si,
    const float* __restrict__ sf, const float* __restrict__ dv,
    const float* __restrict__ di, const float* __restrict__ df,
    unsigned char* __restrict__ Af8, unsigned char* __restrict__ Df8,
    float* __restrict__ pk, float* __restrict__ pd)
{
    __shared__ unsigned short lv[PPB][CCP];
    __shared__ unsigned short li[PPB][CCP];
    __shared__ unsigned short lf[PPB][CCP];
    __shared__ float ssq[3][PPB];
    __shared__ float inv[3][PPB];
    __shared__ float sdesc;

    const int b   = blockIdx.x / (HWN / PPB);
    const int p0  = (blockIdx.x % (HWN / PPB)) * PPB;
    const int tid = threadIdx.x;
    const int q   = tid & 1;           // pixel quad (pixels q*4..q*4+3)
    const int c0  = (tid >> 1) * 2;    // adjacent channel pair c0, c0+1

    if (tid < 3 * PPB) ((float*)ssq)[tid] = 0.0f;
    if (tid == 0) sdesc = 0.0f;
    __syncthreads();

    // Loads: lanes 2m,2m+1 cover 32B contiguous; 1KB/wave-instr.
    const size_t rbase = ((size_t)b * CC + c0) * HWN + p0 + q * 4;
    const floatx4 v0 = *(const floatx4*)(dv + rbase);
    const floatx4 v1 = *(const floatx4*)(dv + rbase + HWN);
    const floatx4 i0 = *(const floatx4*)(di + rbase);
    const floatx4 i1 = *(const floatx4*)(di + rbase + HWN);
    const floatx4 f0 = *(const floatx4*)(df + rbase);
    const floatx4 f1 = *(const floatx4*)(df + rbase + HWN);

    float sqv[4], sqi[4], sqf[4], descp = 0.f;
    #pragma unroll
    for (int k = 0; k < 4; ++k) {
        sqv[k] = v0[k] * v0[k] + v1[k] * v1[k];
        sqi[k] = i0[k] * i0[k] + i1[k] * i1[k];
        sqf[k] = f0[k] * f0[k] + f1[k] * f1[k];
        descp += fabsf(f0[k] - 0.5f * (v0[k] + i0[k]))
               + fabsf(f1[k] - 0.5f * (v1[k] + i1[k]));
        const int p = q * 4 + k;
        // packed bf16 pair -> one ds_write_b32; banks (p*2 + c0/2)%32: 2-way free
        *(unsigned*)&lv[p][c0] = (unsigned)f2bf(v0[k]) | ((unsigned)f2bf(v1[k]) << 16);
        *(unsigned*)&li[p][c0] = (unsigned)f2bf(i0[k]) | ((unsigned)f2bf(i1[k]) << 16);
        *(unsigned*)&lf[p][c0] = (unsigned)f2bf(f0[k]) | ((unsigned)f2bf(f1[k]) << 16);
    }

    // Reduce squares across the 32 channel-pair lanes sharing a pixel quad
    // (stride-2 lanes within the wave), then LDS atomics from lanes 0,1.
    #pragma unroll
    for (int off = 2; off < 64; off <<= 1) {
        #pragma unroll
        for (int k = 0; k < 4; ++k) {
            sqv[k] += __shfl_down(sqv[k], off);
            sqi[k] += __shfl_down(sqi[k], off);
            sqf[k] += __shfl_down(sqf[k], off);
        }
    }
    if ((tid & 63) < 2) {
        #pragma unroll
        for (int k = 0; k < 4; ++k) {
            atomicAdd(&ssq[0][q * 4 + k], sqv[k]);
            atomicAdd(&ssq[1][q * 4 + k], sqi[k]);
            atomicAdd(&ssq[2][q * 4 + k], sqf[k]);
        }
    }

    // desc partial: wave reduce, one LDS atomic per wave
    #pragma unroll
    for (int off = 32; off > 0; off >>= 1) descp += __shfl_down(descp, off);
    if ((tid & 63) == 0) atomicAdd(&sdesc, descp);

    // kp term: this block's 8 pixels (first wave only)
    if (tid < 64) {
        float kpv = 0.f;
        if (tid < PPB) {
            const size_t sidx = (size_t)b * HWN + p0 + tid;
            kpv = fabsf(sf[sidx] - fmaxf(sv[sidx], si[sidx]));
        }
        kpv += __shfl_down(kpv, 4);
        kpv += __shfl_down(kpv, 2);
        kpv += __shfl_down(kpv, 1);
        if (tid == 0) pk[blockIdx.x] = kpv;
    }
    __syncthreads();

    if (tid < 3 * PPB) {
        const float s = ((float*)ssq)[tid];
        ((float*)inv)[tid] = 1.0f / fmaxf(sqrtf(s), 1e-12f);
    }
    __syncthreads();

    if (tid == 0) pd[blockIdx.x] = sdesc;

    // Write phase: 1024 ints total (A+D), 2 per thread per tensor.
    // Wave writes 64 consecutive ints = 256B contiguous. LDS reads are
    // 8B-aligned ds_read_b64, <=4-way banked (1.58x, negligible).
    int* Ao = (int*)(Af8 + (size_t)b * HWN * CC);
    int* Do = (int*)(Df8 + (size_t)b * HWN * CC);
    const int obase = (p0 >> 4) * 1024 + (p0 & 8) * 8;
    #pragma unroll
    for (int s = 0; s < 2; ++s) {
        const int i  = tid + s * 256;
        const int kb = i >> 6, rem = i & 63;
        const int px = rem >> 3, cg = rem & 7;
        const int cs = kb * 32 + cg * 4;
        const float ia = inv[0][px], ibv = inv[1][px], ic = inv[2][px];
        float a0 = bf2f(lv[px][cs + 0]) * ia, a1 = bf2f(lv[px][cs + 1]) * ia;
        float a2 = bf2f(lv[px][cs + 2]) * ia, a3 = bf2f(lv[px][cs + 3]) * ia;
        float d0 = bf2f(lf[px][cs + 0]) * ic - bf2f(li[px][cs + 0]) * ibv;
        float d1 = bf2f(lf[px][cs + 1]) * ic - bf2f(li[px][cs + 1]) * ibv;
        float d2 = bf2f(lf[px][cs + 2]) * ic - bf2f(li[px][cs + 2]) * ibv;
        float d3 = bf2f(lf[px][cs + 3]) * ic - bf2f(li[px][cs + 3]) * ibv;
        int wa = __builtin_amdgcn_cvt_pk_fp8_f32(a0, a1, 0, false);
        wa     = __builtin_amdgcn_cvt_pk_fp8_f32(a2, a3, wa, true);
        int wd = __builtin_amdgcn_cvt_pk_fp8_f32(d0, d1, 0, false);
        wd     = __builtin_amdgcn_cvt_pk_fp8_f32(d2, d3, wd, true);
        const int oidx = obase + kb * 128 + px * 8 + cg;
        Ao[oidx] = wa;
        Do[oidx] = wd;
    }
}

// No-LDS GEMM (unchanged from round 6): one 64x64 tile per wave, fragments
// loaded as 2KB contiguous wave transactions, 32 MFMA, zero barriers.
// |.|-sum epilogue (permutation-invariant) -> per-wave partial store.
__global__ __launch_bounds__(256) void gemm_abs_kernel(
    const unsigned char* __restrict__ Af8,
    const unsigned char* __restrict__ Df8,
    float* __restrict__ pg)
{
    const int b    = blockIdx.z;
    const int tid  = threadIdx.x;
    const int wave = tid >> 6;
    const int lane = tid & 63;
    const int wr   = wave >> 1, wc = wave & 1;
    const int mg0  = blockIdx.x * 8 + wr * 4;   // row-group (of 16) base
    const int ng0  = blockIdx.y * 8 + wc * 4;

    const unsigned char* Ab = Af8 + (size_t)b * HWN * CC;
    const unsigned char* Db = Df8 + (size_t)b * HWN * CC;
    const int lofs = (lane >> 4) * 512 + (lane & 15) * 32;

    intx4 a[4][2][2], bb[4][2][2];
    #pragma unroll
    for (int mi = 0; mi < 4; ++mi)
        #pragma unroll
        for (int ks = 0; ks < 2; ++ks) {
            const unsigned char* pa = Ab + (size_t)(mg0 + mi) * 4096
                                    + ks * 2048 + lofs;
            a[mi][ks][0] = *(const intx4*)(pa);
            a[mi][ks][1] = *(const intx4*)(pa + 16);
        }
    #pragma unroll
    for (int ni = 0; ni < 4; ++ni)
        #pragma unroll
        for (int ks = 0; ks < 2; ++ks) {
            const unsigned char* pb = Db + (size_t)(ng0 + ni) * 4096
                                    + ks * 2048 + lofs;
            bb[ni][ks][0] = *(const intx4*)(pb);
            bb[ni][ks][1] = *(const intx4*)(pb + 16);
        }

    floatx4 accf[4][4];
    #pragma unroll
    for (int mi = 0; mi < 4; ++mi)
        #pragma unroll
        for (int ni = 0; ni < 4; ++ni)
            accf[mi][ni] = (floatx4){0.f, 0.f, 0.f, 0.f};

    #pragma unroll
    for (int ks = 0; ks < 2; ++ks)
        #pragma unroll
        for (int mi = 0; mi < 4; ++mi) {
            const intx8 a8 = __builtin_shufflevector(
                a[mi][ks][0], a[mi][ks][1], 0, 1, 2, 3, 4, 5, 6, 7);
            #pragma unroll
            for (int ni = 0; ni < 4; ++ni) {
                const intx8 b8 = __builtin_shufflevector(
                    bb[ni][ks][0], bb[ni][ks][1], 0, 1, 2, 3, 4, 5, 6, 7);
                accf[mi][ni] = __builtin_amdgcn_mfma_scale_f32_16x16x128_f8f6f4(
                    a8, b8, accf[mi][ni],
                    0, 0,                      // cbsz=fp8, blgp=fp8
                    0, 0x7F7F7F7F,             // A scales: E8M0 1.0
                    0, 0x7F7F7F7F);            // B scales: E8M0 1.0
            }
        }

    float s = 0.f;
    #pragma unroll
    for (int mi = 0; mi < 4; ++mi)
        #pragma unroll
        for (int ni = 0; ni < 4; ++ni)
            #pragma unroll
            for (int r = 0; r < 4; ++r)
                s += fabsf(accf[mi][ni][r]);
    #pragma unroll
    for (int off = 32; off > 0; off >>= 1) s += __shfl_down(s, off);
    if (lane == 0) {
        const int flat = blockIdx.x + 32 * (blockIdx.y + 32 * blockIdx.z);
        pg[flat * 4 + wave] = s;   // per-wave partial, zero contention
    }
}

// Single block: reduce 8192 match + 1024 kp + 1024 desc partials.
__global__ __launch_bounds__(256) void final_kernel(
    const float* __restrict__ pg, const float* __restrict__ pk,
    const float* __restrict__ pd, float* __restrict__ out)
{
    __shared__ float ws[4];
    const int t = threadIdx.x;
    float s = 0.f;
    #pragma unroll
    for (int i = 0; i < 32; ++i)
        s += pg[t + i * 256];
    s *= (1.0f / 33554432.0f);                 // match / (B*HW*HW)
    float kd = 0.f;
    #pragma unroll
    for (int i = 0; i < 4; ++i)
        kd += pk[t + i * 256] * (1.0f / 8192.0f)
            + pd[t + i * 256] * (1.0f / 2097152.0f);
    s += kd;
    #pragma unroll
    for (int off = 32; off > 0; off >>= 1) s += __shfl_down(s, off);
    if ((t & 63) == 0) ws[t >> 6] = s;
    __syncthreads();
    if (t == 0) out[0] = ws[0] + ws[1] + ws[2] + ws[3];
}

extern "C" void kernel_launch(void* const* d_in, const int* in_sizes, int n_in,
                              void* d_out, int out_size, void* d_ws, size_t ws_size,
                              hipStream_t stream) {
    const float* sv = (const float*)d_in[0];
    const float* si = (const float*)d_in[1];
    const float* sf = (const float*)d_in[2];
    const float* dv = (const float*)d_in[3];
    const float* di = (const float*)d_in[4];
    const float* df = (const float*)d_in[5];

    unsigned char* Af8 = (unsigned char*)d_ws;                 // 2 MB
    unsigned char* Df8 = Af8 + (size_t)BB * HWN * CC;          // 2 MB
    float* pg = (float*)(Df8 + (size_t)BB * HWN * CC);         // 32 KB (8192)
    float* pk = pg + 8192;                                     // 4 KB (1024)
    float* pd = pk + 1024;                                     // 4 KB (1024)

    prep_kernel<<<dim3(BB * (HWN / PPB)), 256, 0, stream>>>(
        sv, si, sf, dv, di, df, Af8, Df8, pk, pd);
    gemm_abs_kernel<<<dim3(HWN / 128, HWN / 128, BB), 256, 0, stream>>>(
        Af8, Df8, pg);
    final_kernel<<<1, 256, 0, stream>>>(pg, pk, pd, (float*)d_out);
}

// Round 9
// 102.038 us; speedup vs baseline: 1.0497x; 1.0497x over previous
//
#include <hip/hip_runtime.h>
#include <hip/hip_bf16.h>
#include <math.h>

// Problem constants: B=2, C=256, H=W=64 -> HW=4096
#define BB 2
#define CC 256
#define HWN 4096
#define PPB 16             // pixels per prep block -> grid 512 = 2 blocks/CU
#define CCP 260            // stash stride (shorts): 520B = 130 words -> store
                           // bank = (2p + chp)%32, 2-way (free); 8B-aligned rows

// Fragment-blocked fp8 layout (per batch): for row r (pixel), k-byte kb:
//   addr = (r>>4)*4096 + (kb>>5)*512 + (r&15)*32 + (kb&31)
// => an MFMA fragment load (16 rows x 32 k-bytes, lane L: row L&15,
//    kb (L>>4)*32) is ONE contiguous 2KB wave transaction. No LDS needed.

typedef __attribute__((ext_vector_type(4))) int   intx4;
typedef __attribute__((ext_vector_type(8))) int   intx8;
typedef __attribute__((ext_vector_type(4))) float floatx4;

__device__ __forceinline__ unsigned short f2bf(float f) {
    union { float f; unsigned u; } v; v.f = f;
    unsigned r = v.u + 0x7FFF + ((v.u >> 16) & 1);   // RNE
    return (unsigned short)(r >> 16);
}

__device__ __forceinline__ float bf2f(unsigned short h) {
    union { unsigned u; float f; } v; v.u = ((unsigned)h) << 16;
    return v.f;
}

// Fused prep: one block per (batch, 16-pixel chunk), 256 threads, ~25 KB LDS
// -> 2 blocks/CU so phase chains pipeline across blocks. Load mapping keeps
// FULL 64B segments (R8 lesson: 32B segments = 2x read amplification):
// lanes 0..3 cover 16 pixels of one channel row. Each thread handles 4
// channels (c0, c0+1, c0+128, c0+129) x its 4-pixel quad.
__global__ __launch_bounds__(256) void prep_kernel(
    const float* __restrict__ sv, const float* __restrict__ si,
    const float* __restrict__ sf, const float* __restrict__ dv,
    const float* __restrict__ di, const float* __restrict__ df,
    unsigned char* __restrict__ Af8, unsigned char* __restrict__ Df8,
    float* __restrict__ pk, float* __restrict__ pd)
{
    __shared__ unsigned short lv[PPB][CCP];
    __shared__ unsigned short li[PPB][CCP];
    __shared__ unsigned short lf[PPB][CCP];
    __shared__ float ssq[3][PPB];
    __shared__ float inv[3][PPB];
    __shared__ float sdesc;

    const int b   = blockIdx.x / (HWN / PPB);
    const int p0  = (blockIdx.x % (HWN / PPB)) * PPB;
    const int tid = threadIdx.x;
    const int tp  = tid & 3;           // pixel quad: pixels tp*4..tp*4+3
    const int c0  = (tid >> 2) * 2;    // channel pair base in [0,128)

    if (tid < 3 * PPB) ((float*)ssq)[tid] = 0.0f;
    if (tid == 0) sdesc = 0.0f;
    __syncthreads();

    float sq[3][4] = {};
    float descp = 0.f;
    #pragma unroll
    for (int h = 0; h < 2; ++h) {
        const int ch = c0 + h * 128;
        const size_t rbase = ((size_t)b * CC + ch) * HWN + p0 + tp * 4;
        const floatx4 v0 = *(const floatx4*)(dv + rbase);
        const floatx4 v1 = *(const floatx4*)(dv + rbase + HWN);
        const floatx4 i0 = *(const floatx4*)(di + rbase);
        const floatx4 i1 = *(const floatx4*)(di + rbase + HWN);
        const floatx4 f0 = *(const floatx4*)(df + rbase);
        const floatx4 f1 = *(const floatx4*)(df + rbase + HWN);
        #pragma unroll
        for (int k = 0; k < 4; ++k) {
            sq[0][k] += v0[k] * v0[k] + v1[k] * v1[k];
            sq[1][k] += i0[k] * i0[k] + i1[k] * i1[k];
            sq[2][k] += f0[k] * f0[k] + f1[k] * f1[k];
            descp += fabsf(f0[k] - 0.5f * (v0[k] + i0[k]))
                   + fabsf(f1[k] - 0.5f * (v1[k] + i1[k]));
            const int p = tp * 4 + k;
            // packed bf16 pair -> one ds_write_b32, 2-way banked (free)
            *(unsigned*)&lv[p][ch] = (unsigned)f2bf(v0[k]) | ((unsigned)f2bf(v1[k]) << 16);
            *(unsigned*)&li[p][ch] = (unsigned)f2bf(i0[k]) | ((unsigned)f2bf(i1[k]) << 16);
            *(unsigned*)&lf[p][ch] = (unsigned)f2bf(f0[k]) | ((unsigned)f2bf(f1[k]) << 16);
        }
    }

    // Reduce squares across the 16 stride-4 lanes sharing a pixel quad.
    #pragma unroll
    for (int off = 4; off < 64; off <<= 1) {
        #pragma unroll
        for (int j = 0; j < 3; ++j)
            #pragma unroll
            for (int k = 0; k < 4; ++k)
                sq[j][k] += __shfl_down(sq[j][k], off);
    }
    if ((tid & 63) < 4) {
        #pragma unroll
        for (int j = 0; j < 3; ++j)
            #pragma unroll
            for (int k = 0; k < 4; ++k)
                atomicAdd(&ssq[j][tp * 4 + k], sq[j][k]);
    }

    // desc partial: wave reduce, one LDS atomic per wave
    #pragma unroll
    for (int off = 32; off > 0; off >>= 1) descp += __shfl_down(descp, off);
    if ((tid & 63) == 0) atomicAdd(&sdesc, descp);

    // kp term: this block's 16 pixels (first wave only)
    if (tid < 64) {
        float kpv = 0.f;
        if (tid < PPB) {
            const size_t sidx = (size_t)b * HWN + p0 + tid;
            kpv = fabsf(sf[sidx] - fmaxf(sv[sidx], si[sidx]));
        }
        kpv += __shfl_down(kpv, 8);
        kpv += __shfl_down(kpv, 4);
        kpv += __shfl_down(kpv, 2);
        kpv += __shfl_down(kpv, 1);
        if (tid == 0) pk[blockIdx.x] = kpv;
    }
    __syncthreads();

    if (tid < 3 * PPB) {
        const float s = ((float*)ssq)[tid];
        ((float*)inv)[tid] = 1.0f / fmaxf(sqrtf(s), 1e-12f);
    }
    __syncthreads();

    if (tid == 0) pd[blockIdx.x] = sdesc;

    // Write phase: 1024 ints per tensor; 4 per thread. Wave writes 64
    // consecutive ints (256B contiguous). Stash reads are 8B-aligned
    // ds_read_b64 (CCP=260 keeps rows 8B-aligned).
    int* Ao = (int*)(Af8 + (size_t)b * HWN * CC);
    int* Do = (int*)(Df8 + (size_t)b * HWN * CC);
    const int obase = (p0 >> 4) * 1024;
    #pragma unroll
    for (int s = 0; s < 4; ++s) {
        const int i   = tid + s * 256;
        const int kb  = i >> 7;               // 32-channel block 0..7
        const int rem = i & 127;
        const int px  = rem >> 3, cg = rem & 7;
        const int cs  = kb * 32 + cg * 4;
        const float ia = inv[0][px], ibv = inv[1][px], ic = inv[2][px];
        float a0 = bf2f(lv[px][cs + 0]) * ia, a1 = bf2f(lv[px][cs + 1]) * ia;
        float a2 = bf2f(lv[px][cs + 2]) * ia, a3 = bf2f(lv[px][cs + 3]) * ia;
        float d0 = bf2f(lf[px][cs + 0]) * ic - bf2f(li[px][cs + 0]) * ibv;
        float d1 = bf2f(lf[px][cs + 1]) * ic - bf2f(li[px][cs + 1]) * ibv;
        float d2 = bf2f(lf[px][cs + 2]) * ic - bf2f(li[px][cs + 2]) * ibv;
        float d3 = bf2f(lf[px][cs + 3]) * ic - bf2f(li[px][cs + 3]) * ibv;
        int wa = __builtin_amdgcn_cvt_pk_fp8_f32(a0, a1, 0, false);
        wa     = __builtin_amdgcn_cvt_pk_fp8_f32(a2, a3, wa, true);
        int wd = __builtin_amdgcn_cvt_pk_fp8_f32(d0, d1, 0, false);
        wd     = __builtin_amdgcn_cvt_pk_fp8_f32(d2, d3, wd, true);
        const int oidx = obase + kb * 128 + px * 8 + cg;
        Ao[oidx] = wa;
        Do[oidx] = wd;
    }
}

// No-LDS GEMM, widened wave tile 64x128: A fragments loaded once per
// K-half feed 8 B-columns (1.33x less traffic per output, half the waves,
// loads hidden under 4x ~34cyc MFMAs). Block = 2x2 waves = 128x256 tile.
// Fragments are 2KB contiguous wave transactions; zero barriers/atomics.
// |.|-sum epilogue (permutation-invariant) -> per-wave partial store.
__global__ __launch_bounds__(256) void gemm_abs_kernel(
    const unsigned char* __restrict__ Af8,
    const unsigned char* __restrict__ Df8,
    float* __restrict__ pg)
{
    const int b    = blockIdx.z;
    const int tid  = threadIdx.x;
    const int wave = tid >> 6;
    const int lane = tid & 63;
    const int wr   = wave >> 1, wc = wave & 1;
    const int mg0  = blockIdx.x * 8 + wr * 4;    // 4 row-groups = 64 rows
    const int ng0  = blockIdx.y * 16 + wc * 8;   // 8 row-groups = 128 rows

    const unsigned char* Ab = Af8 + (size_t)b * HWN * CC;
    const unsigned char* Db = Df8 + (size_t)b * HWN * CC;
    const int lofs = (lane >> 4) * 512 + (lane & 15) * 32;

    floatx4 accf[4][8];
    #pragma unroll
    for (int mi = 0; mi < 4; ++mi)
        #pragma unroll
        for (int ni = 0; ni < 8; ++ni)
            accf[mi][ni] = (floatx4){0.f, 0.f, 0.f, 0.f};

    #pragma unroll
    for (int ks = 0; ks < 2; ++ks) {
        intx8 a8[4];
        #pragma unroll
        for (int mi = 0; mi < 4; ++mi) {
            const unsigned char* pa = Ab + (size_t)(mg0 + mi) * 4096
                                    + ks * 2048 + lofs;
            const intx4 lo = *(const intx4*)(pa);
            const intx4 hi = *(const intx4*)(pa + 16);
            a8[mi] = __builtin_shufflevector(lo, hi, 0, 1, 2, 3, 4, 5, 6, 7);
        }
        #pragma unroll
        for (int ni = 0; ni < 8; ++ni) {
            const unsigned char* pb = Db + (size_t)(ng0 + ni) * 4096
                                    + ks * 2048 + lofs;
            const intx4 lo = *(const intx4*)(pb);
            const intx4 hi = *(const intx4*)(pb + 16);
            const intx8 b8 = __builtin_shufflevector(lo, hi, 0, 1, 2, 3, 4, 5, 6, 7);
            #pragma unroll
            for (int mi = 0; mi < 4; ++mi)
                accf[mi][ni] = __builtin_amdgcn_mfma_scale_f32_16x16x128_f8f6f4(
                    a8[mi], b8, accf[mi][ni],
                    0, 0,                      // cbsz=fp8, blgp=fp8
                    0, 0x7F7F7F7F,             // A scales: E8M0 1.0
                    0, 0x7F7F7F7F);            // B scales: E8M0 1.0
        }
    }

    float s = 0.f;
    #pragma unroll
    for (int mi = 0; mi < 4; ++mi)
        #pragma unroll
        for (int ni = 0; ni < 8; ++ni)
            #pragma unroll
            for (int r = 0; r < 4; ++r)
                s += fabsf(accf[mi][ni][r]);
    #pragma unroll
    for (int off = 32; off > 0; off >>= 1) s += __shfl_down(s, off);
    if (lane == 0) {
        const int flat = blockIdx.x + 32 * (blockIdx.y + 16 * blockIdx.z);
        pg[flat * 4 + wave] = s;   // per-wave partial, zero contention
    }
}

// Single block: reduce 4096 match + 512 kp + 512 desc partials.
__global__ __launch_bounds__(256) void final_kernel(
    const float* __restrict__ pg, const float* __restrict__ pk,
    const float* __restrict__ pd, float* __restrict__ out)
{
    __shared__ float ws[4];
    const int t = threadIdx.x;
    float s = 0.f;
    #pragma unroll
    for (int i = 0; i < 16; ++i)
        s += pg[t + i * 256];
    s *= (1.0f / 33554432.0f);                 // match / (B*HW*HW)
    #pragma unroll
    for (int i = 0; i < 2; ++i)
        s += pk[t + i * 256] * (1.0f / 8192.0f)
           + pd[t + i * 256] * (1.0f / 2097152.0f);
    #pragma unroll
    for (int off = 32; off > 0; off >>= 1) s += __shfl_down(s, off);
    if ((t & 63) == 0) ws[t >> 6] = s;
    __syncthreads();
    if (t == 0) out[0] = ws[0] + ws[1] + ws[2] + ws[3];
}

extern "C" void kernel_launch(void* const* d_in, const int* in_sizes, int n_in,
                              void* d_out, int out_size, void* d_ws, size_t ws_size,
                              hipStream_t stream) {
    const float* sv = (const float*)d_in[0];
    const float* si = (const float*)d_in[1];
    const float* sf = (const float*)d_in[2];
    const float* dv = (const float*)d_in[3];
    const float* di = (const float*)d_in[4];
    const float* df = (const float*)d_in[5];

    unsigned char* Af8 = (unsigned char*)d_ws;                 // 2 MB
    unsigned char* Df8 = Af8 + (size_t)BB * HWN * CC;          // 2 MB
    float* pg = (float*)(Df8 + (size_t)BB * HWN * CC);         // 16 KB (4096)
    float* pk = pg + 4096;                                     // 2 KB (512)
    float* pd = pk + 512;                                      // 2 KB (512)

    prep_kernel<<<dim3(BB * (HWN / PPB)), 256, 0, stream>>>(
        sv, si, sf, dv, di, df, Af8, Df8, pk, pd);
    gemm_abs_kernel<<<dim3(HWN / 128, HWN / 256, BB), 256, 0, stream>>>(
        Af8, Df8, pg);
    final_kernel<<<1, 256, 0, stream>>>(pg, pk, pd, (float*)d_out);
}